// Round 1
// baseline (95.504 us; speedup 1.0000x reference)
//
#include <hip/hip_runtime.h>

typedef float f32x4 __attribute__((ext_vector_type(4)));
typedef short bf16x8 __attribute__((ext_vector_type(8)));

__device__ __forceinline__ ushort f2bf(float f) {
  union { float f; unsigned u; } x; x.f = f;
  unsigned r = x.u + 0x7fffu + ((x.u >> 16) & 1u);  // RNE to bf16
  return (ushort)(r >> 16);
}

// Pack weights into MFMA A-fragment order:
// wpk[((layer*8 + jt)*4 + kt)*64 + lane][i]  = W[kt*32 + 8*(lane>>4) + i][jt*16 + (lane&15)]
// (K padded 127->128 with zeros for layer 0)
__global__ void pack_w(const float* __restrict__ W0, const float* __restrict__ W1,
                       const float* __restrict__ W2, const float* __restrict__ W3,
                       ushort* __restrict__ wpk) {
  int t = blockIdx.x * 256 + threadIdx.x;
  if (t >= 4 * 8 * 4 * 64) return;
  int lane = t & 63, kt = (t >> 6) & 3, jt = (t >> 8) & 7, layer = t >> 11;
  const float* W = layer == 0 ? W0 : layer == 1 ? W1 : layer == 2 ? W2 : W3;
  int K = (layer == 0) ? 127 : 128;
  int g = lane >> 4, r = lane & 15;
  bf16x8 pk;
#pragma unroll
  for (int i = 0; i < 8; i++) {
    int k = kt * 32 + 8 * g + i;
    pk[i] = (short)((k < K) ? f2bf(W[k * 128 + jt * 16 + r]) : (ushort)0);
  }
  *(bf16x8*)(wpk + t * 8) = pk;
}

__global__ __launch_bounds__(256, 2) void scene_fwd(
    const float* __restrict__ xyz, const float* __restrict__ lat,
    const ushort* __restrict__ wpk,
    const float* __restrict__ b0, const float* __restrict__ b1,
    const float* __restrict__ b2, const float* __restrict__ b3,
    const float* __restrict__ wa, const float* __restrict__ ba,
    float* __restrict__ out) {
  // wave-private activation tile: h[64 points][128 ch] bf16, rows 256B,
  // byte-XOR swizzle ((row&7)<<4) on the within-row offset.
  __shared__ ushort hbuf[4][64 * 128];  // 64 KB
  const int tid = threadIdx.x;
  const int wave = tid >> 6, lane = tid & 63;
  char* hb = (char*)hbuf[wave];
  const int g = lane >> 4, r = lane & 15;
  const int p0 = blockIdx.x * 256 + wave * 64;

  // ---------------- feature phase: one thread = one point ----------------
  {
    const int p = p0 + lane;
    const float X = xyz[3 * p + 0], Y = xyz[3 * p + 1], Z = xyz[3 * p + 2];
    const float* img = lat + (p >> 16) * (64 * 256);  // batch = p/65536
    // grid_sample coords (align_corners=False style, border-zero)
    float gx = (X + 1.f) * 8.f - 0.5f;
    float gy = (Z + 1.f) * 8.f - 0.5f;
    float x0f = floorf(gx), y0f = floorf(gy);
    float fx = gx - x0f, fy = gy - y0f;
    int ix0 = (int)x0f, iy0 = (int)y0f;
    int ix1 = ix0 + 1, iy1 = iy0 + 1;
    float vx0 = (ix0 >= 0 && ix0 <= 15) ? 1.f : 0.f;
    float vx1 = (ix1 >= 0 && ix1 <= 15) ? 1.f : 0.f;
    float vy0 = (iy0 >= 0 && iy0 <= 15) ? 1.f : 0.f;
    float vy1 = (iy1 >= 0 && iy1 <= 15) ? 1.f : 0.f;
    int cx0 = min(max(ix0, 0), 15), cx1 = min(max(ix1, 0), 15);
    int cy0 = min(max(iy0, 0), 15), cy1 = min(max(iy1, 0), 15);
    float w00 = (1.f - fx) * (1.f - fy) * vx0 * vy0;
    float w01 = (1.f - fx) * fy * vx0 * vy1;
    float w10 = fx * (1.f - fy) * vx1 * vy0;
    float w11 = fx * fy * vx1 * vy1;
    int i00 = cy0 * 16 + cx0, i01 = cy1 * 16 + cx0;
    int i10 = cy0 * 16 + cx1, i11 = cy1 * 16 + cx1;
    const unsigned swz = (unsigned)((lane & 7) << 4);
    char* row = hb + lane * 256;
    // channels 0..63: bilinear latent sample
#pragma unroll
    for (int c8 = 0; c8 < 8; c8++) {
      bf16x8 pk;
#pragma unroll
      for (int i = 0; i < 8; i++) {
        const float* ch = img + (c8 * 8 + i) * 256;
        float v = w00 * ch[i00] + w01 * ch[i01] + w10 * ch[i10] + w11 * ch[i11];
        pk[i] = (short)f2bf(v);
      }
      *(bf16x8*)(row + (((unsigned)(c8 * 16)) ^ swz)) = pk;
    }
    // channels 64..127: [lcx, Y, lcz, sin(2^f*c) f-major, cos(2^f*c), pad0]
    float feat[64];
    float lcx = (X + 1.f) * 8.f; lcx = lcx - rintf(lcx - 0.5f); lcx = lcx * 2.f - 1.f;
    float lcz = (Z + 1.f) * 8.f; lcz = lcz - rintf(lcz - 0.5f); lcz = lcz * 2.f - 1.f;
    feat[0] = lcx; feat[1] = Y; feat[2] = lcz;
    const float cc[3] = {lcx, Y, lcz};
#pragma unroll
    for (int f = 0; f < 10; f++) {
      const float s = (float)(1 << f);
#pragma unroll
      for (int d = 0; d < 3; d++) {
        feat[3 + 3 * f + d]  = __sinf(cc[d] * s);
        feat[33 + 3 * f + d] = __cosf(cc[d] * s);
      }
    }
    feat[63] = 0.f;
#pragma unroll
    for (int c8 = 0; c8 < 8; c8++) {
      bf16x8 pk;
#pragma unroll
      for (int i = 0; i < 8; i++) pk[i] = (short)f2bf(feat[c8 * 8 + i]);
      *(bf16x8*)(row + (((unsigned)(128 + c8 * 16)) ^ swz)) = pk;
    }
  }
  // No barrier: tile is wave-private; per-wave DS ops are in-order.

  // ---------------- MLP: D[j][p] = W^T . h^T  (swapped operands) ----------
  // A-frag (weights, prepacked): lane holds W[kt*32+8g+i][jt*16+r]
  // B-frag (activations): lane reads h[pt*16+r][kt*32+8g .. +7] = 16B from LDS
  // D: lane holds out j = jt*16+4g+i, point = pt*16+r  -> writes back its own rows.
  const float* biases[4] = {b0, b1, b2, b3};
  f32x4 acc[8][4];
#pragma unroll
  for (int layer = 0; layer < 4; layer++) {
    const float* bias = biases[layer];
#pragma unroll
    for (int jt = 0; jt < 8; jt++) {
      f32x4 bf = *(const f32x4*)(bias + jt * 16 + 4 * g);
#pragma unroll
      for (int pt = 0; pt < 4; pt++) acc[jt][pt] = bf;
    }
#pragma unroll
    for (int kt = 0; kt < 4; kt++) {
      bf16x8 Bf[4];
#pragma unroll
      for (int pt = 0; pt < 4; pt++) {
        const int pr = pt * 16 + r;
        Bf[pt] = *(const bf16x8*)(hb + pr * 256 +
                  (((unsigned)(kt * 64 + 16 * g)) ^ ((unsigned)((pr & 7) << 4))));
      }
#pragma unroll
      for (int jt = 0; jt < 8; jt++) {
        bf16x8 Af = *(const bf16x8*)(wpk + (((layer * 8 + jt) * 4 + kt) * 64 + lane) * 8);
#pragma unroll
        for (int pt = 0; pt < 4; pt++)
          acc[jt][pt] = __builtin_amdgcn_mfma_f32_16x16x32_bf16(Af, Bf[pt], acc[jt][pt], 0, 0, 0);
      }
    }
    if (layer < 3) {
      // ReLU + bf16 pack + in-place writeback (4 ch per lane per (jt,pt))
#pragma unroll
      for (int jt = 0; jt < 8; jt++) {
#pragma unroll
        for (int pt = 0; pt < 4; pt++) {
          const int pr = pt * 16 + r;
          unsigned d0 = (unsigned)f2bf(fmaxf(acc[jt][pt][0], 0.f)) |
                        ((unsigned)f2bf(fmaxf(acc[jt][pt][1], 0.f)) << 16);
          unsigned d1 = (unsigned)f2bf(fmaxf(acc[jt][pt][2], 0.f)) |
                        ((unsigned)f2bf(fmaxf(acc[jt][pt][3], 0.f)) << 16);
          uint2 w; w.x = d0; w.y = d1;
          *(uint2*)(hb + pr * 256 +
                    (((unsigned)(32 * jt + 8 * g)) ^ ((unsigned)((pr & 7) << 4)))) = w;
        }
      }
    }
  }
  // ---------------- alpha = relu(h4) @ Wa + ba ----------------
  const float ba0 = ba[0];
  float part[4] = {0.f, 0.f, 0.f, 0.f};
#pragma unroll
  for (int jt = 0; jt < 8; jt++) {
    f32x4 wf = *(const f32x4*)(wa + jt * 16 + 4 * g);
#pragma unroll
    for (int pt = 0; pt < 4; pt++) {
#pragma unroll
      for (int i = 0; i < 4; i++)
        part[pt] += fmaxf(acc[jt][pt][i], 0.f) * wf[i];
    }
  }
#pragma unroll
  for (int pt = 0; pt < 4; pt++) {
    float s = part[pt];
    s += __shfl_xor(s, 16, 64);
    s += __shfl_xor(s, 32, 64);
    if (lane < 16) out[p0 + pt * 16 + lane] = s + ba0;
  }
}

extern "C" void kernel_launch(void* const* d_in, const int* in_sizes, int n_in,
                              void* d_out, int out_size, void* d_ws, size_t ws_size,
                              hipStream_t stream) {
  const float* xyz = (const float*)d_in[0];
  const float* lat = (const float*)d_in[1];
  const float* W0 = (const float*)d_in[2];
  const float* b0 = (const float*)d_in[3];
  const float* W1 = (const float*)d_in[4];
  const float* b1 = (const float*)d_in[5];
  const float* W2 = (const float*)d_in[6];
  const float* b2 = (const float*)d_in[7];
  const float* W3 = (const float*)d_in[8];
  const float* b3 = (const float*)d_in[9];
  const float* wa = (const float*)d_in[10];
  const float* ba = (const float*)d_in[11];
  float* out = (float*)d_out;
  ushort* wpk = (ushort*)d_ws;  // 128 KB packed weights

  pack_w<<<(4 * 8 * 4 * 64 + 255) / 256, 256, 0, stream>>>(W0, W1, W2, W3, wpk);
  scene_fwd<<<262144 / 256, 256, 0, stream>>>(xyz, lat, wpk, b0, b1, b2, b3, wa, ba, out);
}

// Round 2
// 67.035 us; speedup vs baseline: 1.4247x; 1.4247x over previous
//
#include <hip/hip_runtime.h>

typedef float f32x4 __attribute__((ext_vector_type(4)));
typedef short bf16x8 __attribute__((ext_vector_type(8)));

__device__ __forceinline__ ushort f2bf(float f) {
  union { float f; unsigned u; } x; x.f = f;
  unsigned r = x.u + 0x7fffu + ((x.u >> 16) & 1u);  // RNE to bf16
  return (ushort)(r >> 16);
}

// One pack kernel, two jobs:
//  t < 8192: weights -> MFMA A-fragment order (bf16, K padded 127->128)
//  t >= 8192: latents -> pixel-major, LDS-swizzled fp32:
//     latpk[b] byte offset pix*256 + (16k ^ ((pix&7)<<4)) holds ch 4k..4k+3
__global__ void pack_all(const float* __restrict__ W0, const float* __restrict__ W1,
                         const float* __restrict__ W2, const float* __restrict__ W3,
                         const float* __restrict__ lat,
                         ushort* __restrict__ wpk, float* __restrict__ latpk) {
  int t = blockIdx.x * 256 + threadIdx.x;
  if (t < 8192) {
    int lane = t & 63, kt = (t >> 6) & 3, jt = (t >> 8) & 7, layer = t >> 11;
    const float* W = layer == 0 ? W0 : layer == 1 ? W1 : layer == 2 ? W2 : W3;
    int K = (layer == 0) ? 127 : 128;
    int g = lane >> 4, r = lane & 15;
    bf16x8 pk;
#pragma unroll
    for (int i = 0; i < 8; i++) {
      int k = kt * 32 + 8 * g + i;
      pk[i] = (short)((k < K) ? f2bf(W[k * 128 + jt * 16 + r]) : (ushort)0);
    }
    *(bf16x8*)(wpk + t * 8) = pk;
  } else if (t < 8192 + 16384) {
    int t2 = t - 8192;
    int k = t2 & 15, pix = (t2 >> 4) & 255, b = t2 >> 12;
    f32x4 v;
#pragma unroll
    for (int i = 0; i < 4; i++) v[i] = lat[(b * 64 + 4 * k + i) * 256 + pix];
    *(f32x4*)((char*)latpk + b * 65536 + pix * 256 + ((16 * k) ^ ((pix & 7) << 4))) = v;
  }
}

__global__ __launch_bounds__(256, 2) void scene_fwd(
    const float* __restrict__ xyz, const float* __restrict__ latpk,
    const ushort* __restrict__ wpk,
    const float* __restrict__ b0, const float* __restrict__ b1,
    const float* __restrict__ b2, const float* __restrict__ b3,
    const float* __restrict__ wa, const float* __restrict__ ba,
    float* __restrict__ out) {
  // 64 KB LDS, two overlapping uses fenced by barriers:
  //   phase A: fp32 latent tile for this block's batch (swizzled, 64 KB)
  //   phase B: 4 wave-private activation tiles h[64][128] bf16 (16 KB each)
  __shared__ char smem[65536];
  const int tid = threadIdx.x;
  const int wave = tid >> 6, lane = tid & 63;
  char* hb = smem + wave * 16384;
  const int g = lane >> 4, r = lane & 15;
  const int p0 = blockIdx.x * 256 + wave * 64;
  const int batch = blockIdx.x >> 8;

  // ---- stage latent tile (linear 64 KB copy, conflict-free) ----
  {
    uint4* dst = (uint4*)smem;
    const uint4* src = (const uint4*)((const char*)latpk + batch * 65536);
#pragma unroll
    for (int i = 0; i < 16; i++) dst[i * 256 + tid] = src[i * 256 + tid];
  }
  __syncthreads();

  // ---- per-point features into registers ----
  const int p = p0 + lane;
  const float X = xyz[3 * p + 0], Y = xyz[3 * p + 1], Z = xyz[3 * p + 2];
  bf16x8 zpk[8];   // 64 latent channels, bf16-packed
  bf16x8 fpk[8];   // 64 PE features, bf16-packed
  {
    float gx = (X + 1.f) * 8.f - 0.5f;
    float gy = (Z + 1.f) * 8.f - 0.5f;
    float x0f = floorf(gx), y0f = floorf(gy);
    float fx = gx - x0f, fy = gy - y0f;
    int ix0 = (int)x0f, iy0 = (int)y0f;
    int ix1 = ix0 + 1, iy1 = iy0 + 1;
    float vx0 = (ix0 >= 0 && ix0 <= 15) ? 1.f : 0.f;
    float vx1 = (ix1 >= 0 && ix1 <= 15) ? 1.f : 0.f;
    float vy0 = (iy0 >= 0 && iy0 <= 15) ? 1.f : 0.f;
    float vy1 = (iy1 >= 0 && iy1 <= 15) ? 1.f : 0.f;
    int cx0 = min(max(ix0, 0), 15), cx1 = min(max(ix1, 0), 15);
    int cy0 = min(max(iy0, 0), 15), cy1 = min(max(iy1, 0), 15);
    float w00 = (1.f - fx) * (1.f - fy) * vx0 * vy0;
    float w01 = (1.f - fx) * fy * vx0 * vy1;
    float w10 = fx * (1.f - fy) * vx1 * vy0;
    float w11 = fx * fy * vx1 * vy1;
    int px00 = cy0 * 16 + cx0, px01 = cy1 * 16 + cx0;
    int px10 = cy0 * 16 + cx1, px11 = cy1 * 16 + cx1;
    int o00 = px00 * 256, s00 = (px00 & 7) << 4;
    int o01 = px01 * 256, s01 = (px01 & 7) << 4;
    int o10 = px10 * 256, s10 = (px10 & 7) << 4;
    int o11 = px11 * 256, s11 = (px11 & 7) << 4;
    // 8 channels per iteration (two f32x4 granules), 4 corners each
#pragma unroll
    for (int k2 = 0; k2 < 8; k2++) {
      f32x4 a0, a1;
#pragma unroll
      for (int h = 0; h < 2; h++) {
        const int kk = 2 * k2 + h;
        const int off = 16 * kk;
        f32x4 c00 = *(const f32x4*)(smem + o00 + (off ^ s00));
        f32x4 c01 = *(const f32x4*)(smem + o01 + (off ^ s01));
        f32x4 c10 = *(const f32x4*)(smem + o10 + (off ^ s10));
        f32x4 c11 = *(const f32x4*)(smem + o11 + (off ^ s11));
        f32x4 acc;
#pragma unroll
        for (int i = 0; i < 4; i++)
          acc[i] = w00 * c00[i] + w01 * c01[i] + w10 * c10[i] + w11 * c11[i];
        if (h == 0) a0 = acc; else a1 = acc;
      }
      bf16x8 pk;
#pragma unroll
      for (int i = 0; i < 4; i++) { pk[i] = (short)f2bf(a0[i]); pk[4 + i] = (short)f2bf(a1[i]); }
      zpk[k2] = pk;
    }
    // PE features: [lcx, Y, lcz, sin(c*2^f) f-major, cos(c*2^f), pad0]
    float feat[64];
    float lcx = (X + 1.f) * 8.f; lcx = lcx - rintf(lcx - 0.5f); lcx = lcx * 2.f - 1.f;
    float lcz = (Z + 1.f) * 8.f; lcz = lcz - rintf(lcz - 0.5f); lcz = lcz * 2.f - 1.f;
    feat[0] = lcx; feat[1] = Y; feat[2] = lcz;
    const float cc[3] = {lcx, Y, lcz};
#pragma unroll
    for (int f = 0; f < 10; f++) {
      const float s = (float)(1 << f);
#pragma unroll
      for (int d = 0; d < 3; d++) {
        feat[3 + 3 * f + d]  = __sinf(cc[d] * s);
        feat[33 + 3 * f + d] = __cosf(cc[d] * s);
      }
    }
    feat[63] = 0.f;
#pragma unroll
    for (int k2 = 0; k2 < 8; k2++) {
      bf16x8 pk;
#pragma unroll
      for (int i = 0; i < 8; i++) pk[i] = (short)f2bf(feat[k2 * 8 + i]);
      fpk[k2] = pk;
    }
  }
  __syncthreads();  // all gathers done before latent tile is overwritten

  // ---- write h[64][128] bf16 (swizzled rows, wave-private) ----
  {
    const unsigned swz = (unsigned)((lane & 7) << 4);
    char* row = hb + lane * 256;
#pragma unroll
    for (int k2 = 0; k2 < 8; k2++)
      *(bf16x8*)(row + (((unsigned)(k2 * 16)) ^ swz)) = zpk[k2];
#pragma unroll
    for (int k2 = 0; k2 < 8; k2++)
      *(bf16x8*)(row + (((unsigned)(128 + k2 * 16)) ^ swz)) = fpk[k2];
  }
  // No barrier: tile is wave-private; per-wave DS ops are in-order.

  // ---- MLP: D[j][p] = W^T . h^T (swapped operands) ----
  const float* biases[4] = {b0, b1, b2, b3};
  f32x4 acc[8][4];
#pragma unroll
  for (int layer = 0; layer < 4; layer++) {
    const float* bias = biases[layer];
#pragma unroll
    for (int jt = 0; jt < 8; jt++) {
      f32x4 bf = *(const f32x4*)(bias + jt * 16 + 4 * g);
#pragma unroll
      for (int pt = 0; pt < 4; pt++) acc[jt][pt] = bf;
    }
#pragma unroll
    for (int kt = 0; kt < 4; kt++) {
      bf16x8 Bf[4];
#pragma unroll
      for (int pt = 0; pt < 4; pt++) {
        const int pr = pt * 16 + r;
        Bf[pt] = *(const bf16x8*)(hb + pr * 256 +
                  (((unsigned)(kt * 64 + 16 * g)) ^ ((unsigned)((pr & 7) << 4))));
      }
#pragma unroll
      for (int jt = 0; jt < 8; jt++) {
        bf16x8 Af = *(const bf16x8*)(wpk + (((layer * 8 + jt) * 4 + kt) * 64 + lane) * 8);
#pragma unroll
        for (int pt = 0; pt < 4; pt++)
          acc[jt][pt] = __builtin_amdgcn_mfma_f32_16x16x32_bf16(Af, Bf[pt], acc[jt][pt], 0, 0, 0);
      }
    }
    if (layer < 3) {
#pragma unroll
      for (int jt = 0; jt < 8; jt++) {
#pragma unroll
        for (int pt = 0; pt < 4; pt++) {
          const int pr = pt * 16 + r;
          unsigned d0 = (unsigned)f2bf(fmaxf(acc[jt][pt][0], 0.f)) |
                        ((unsigned)f2bf(fmaxf(acc[jt][pt][1], 0.f)) << 16);
          unsigned d1 = (unsigned)f2bf(fmaxf(acc[jt][pt][2], 0.f)) |
                        ((unsigned)f2bf(fmaxf(acc[jt][pt][3], 0.f)) << 16);
          uint2 w; w.x = d0; w.y = d1;
          *(uint2*)(hb + pr * 256 +
                    (((unsigned)(32 * jt + 8 * g)) ^ ((unsigned)((pr & 7) << 4)))) = w;
        }
      }
    }
  }
  // ---- alpha = relu(h4) @ Wa + ba ----
  const float ba0 = ba[0];
  float part[4] = {0.f, 0.f, 0.f, 0.f};
#pragma unroll
  for (int jt = 0; jt < 8; jt++) {
    f32x4 wf = *(const f32x4*)(wa + jt * 16 + 4 * g);
#pragma unroll
    for (int pt = 0; pt < 4; pt++) {
#pragma unroll
      for (int i = 0; i < 4; i++)
        part[pt] += fmaxf(acc[jt][pt][i], 0.f) * wf[i];
    }
  }
#pragma unroll
  for (int pt = 0; pt < 4; pt++) {
    float s = part[pt];
    s += __shfl_xor(s, 16, 64);
    s += __shfl_xor(s, 32, 64);
    if (lane < 16) out[p0 + pt * 16 + lane] = s + ba0;
  }
}

extern "C" void kernel_launch(void* const* d_in, const int* in_sizes, int n_in,
                              void* d_out, int out_size, void* d_ws, size_t ws_size,
                              hipStream_t stream) {
  const float* xyz = (const float*)d_in[0];
  const float* lat = (const float*)d_in[1];
  const float* W0 = (const float*)d_in[2];
  const float* b0 = (const float*)d_in[3];
  const float* W1 = (const float*)d_in[4];
  const float* b1 = (const float*)d_in[5];
  const float* W2 = (const float*)d_in[6];
  const float* b2 = (const float*)d_in[7];
  const float* W3 = (const float*)d_in[8];
  const float* b3 = (const float*)d_in[9];
  const float* wa = (const float*)d_in[10];
  const float* ba = (const float*)d_in[11];
  float* out = (float*)d_out;
  ushort* wpk = (ushort*)d_ws;                       // 128 KB packed weights
  float* latpk = (float*)((char*)d_ws + 131072);     // 256 KB packed latents

  pack_all<<<(8192 + 16384 + 255) / 256, 256, 0, stream>>>(W0, W1, W2, W3, lat, wpk, latpk);
  scene_fwd<<<262144 / 256, 256, 0, stream>>>(xyz, latpk, wpk, b0, b1, b2, b3, wa, ba, out);
}